// Round 1
// 1147.884 us; speedup vs baseline: 1.0270x; 1.0270x over previous
//
#include <hip/hip_runtime.h>
#include <cstdint>
#include <cstddef>

// Problem constants
#define B_   8
#define S_   1024
#define D_   1024
#define H_   16
#define HD_  64
#define F_   4096
#define V_   8192
#define KTOP 64

typedef unsigned short ushort_t;
typedef __attribute__((ext_vector_type(8))) short short8;            // MFMA bf16 A/B frag (4 VGPR)
typedef __attribute__((ext_vector_type(8))) _Float16 half8;          // MFMA f16 A/B frag
typedef __attribute__((ext_vector_type(4))) float floatx4;           // MFMA C/D frag
typedef __attribute__((ext_vector_type(4))) unsigned int uintx4;     // 16B copy
typedef __attribute__((ext_vector_type(4))) float floatv4;
typedef __attribute__((ext_vector_type(4))) unsigned short ushortx4;
typedef __attribute__((ext_vector_type(8))) unsigned short ushortx8;

__device__ __forceinline__ ushort_t f2bf(float f) {
    unsigned int u = __builtin_bit_cast(unsigned int, f);
    u += 0x7fffu + ((u >> 16) & 1u);            // round-to-nearest-even
    return (ushort_t)(u >> 16);
}
__device__ __forceinline__ float bf2f(ushort_t u) {
    unsigned int x = ((unsigned int)u) << 16;
    return __builtin_bit_cast(float, x);
}
__device__ __forceinline__ ushort_t f2h(float f) {
    _Float16 h = (_Float16)f;
    return __builtin_bit_cast(ushort_t, h);
}
__device__ __forceinline__ float h2f(ushort_t u) {
    return (float)__builtin_bit_cast(_Float16, u);
}

// async global->LDS, 16B per lane; lds dest = wave-uniform base + lane*16
__device__ __forceinline__ void gload_lds16(const ushort_t* g, ushort_t* lds_base) {
    __builtin_amdgcn_global_load_lds(
        (const __attribute__((address_space(1))) unsigned int*)g,
        (__attribute__((address_space(3))) unsigned int*)lds_base,
        16, 0, 0);
}

// ---------------------------------------------------------------- cast x -> bf16
__global__ __launch_bounds__(256) void cast_x_kernel(const float* __restrict__ x,
                                                     ushort_t* __restrict__ xb) {
    int gid = blockIdx.x * 256 + threadIdx.x;   // 4 elems per thread
    floatv4 v = ((const floatv4*)x)[gid];
    ushortx4 o;
    o[0] = f2bf(v[0]); o[1] = f2bf(v[1]); o[2] = f2bf(v[2]); o[3] = f2bf(v[3]);
    ((ushortx4*)xb)[gid] = o;
}

// ------------------------------------------- transpose + cast weight: W(K,N) -> WT(N,K) bf16, * scale
__global__ void transpose_cast_kernel(const float* __restrict__ W, ushort_t* __restrict__ WT,
                                      int K, int N, float scale) {
    __shared__ float tile[32][33];
    int n0 = blockIdx.x * 32, k0 = blockIdx.y * 32;
    #pragma unroll
    for (int i = threadIdx.y; i < 32; i += 8)
        tile[i][threadIdx.x] = W[(size_t)(k0 + i) * N + n0 + threadIdx.x];
    __syncthreads();
    #pragma unroll
    for (int i = threadIdx.y; i < 32; i += 8)
        WT[(size_t)(n0 + i) * K + k0 + threadIdx.x] = f2bf(tile[threadIdx.x][i] * scale);
}

// ---------------------------------------------------------------- pack q/k/v biases (bq scaled 1/8)
__global__ __launch_bounds__(256) void pack_bias3_kernel(const float* __restrict__ bq,
                                                         const float* __restrict__ bk,
                                                         const float* __restrict__ bv,
                                                         float* __restrict__ o) {
    int i = blockIdx.x * 256 + threadIdx.x;   // 3072 total
    float v = (i < 1024) ? bq[i] * 0.125f : (i < 2048) ? bk[i - 1024] : bv[i - 2048];
    o[i] = v;
}

// ---------------------------------------------------------------- pmi bias gather -> fp16 (ALPHA folded)
__global__ __launch_bounds__(256) void bias_gather_kernel(const int* __restrict__ tok,
                                                          const float* __restrict__ pmi,
                                                          ushort_t* __restrict__ biasb) {
    int b = blockIdx.x >> 10;
    int i = blockIdx.x & (S_ - 1);
    int ti = tok[b * S_ + i];
    const float* prow = pmi + (size_t)ti * V_;
    #pragma unroll
    for (int it = 0; it < 4; it++) {
        int j = threadIdx.x + it * 256;
        int tj = tok[b * S_ + j];
        biasb[(size_t)blockIdx.x * S_ + j] = f2h(0.1f * prow[tj]);
    }
}

// ---------------------------------------------------------------- V (B,H,S,HD) bf16 -> vT (B,H,HD,S) fp16
__global__ __launch_bounds__(256) void transpose_v_kernel(const ushort_t* __restrict__ v,
                                                          ushort_t* __restrict__ vT) {
    __shared__ ushort_t t[64 * 72];   // [s_loc][d], stride 72
    int bh = blockIdx.x >> 4;
    int s0 = (blockIdx.x & 15) * 64;
    #pragma unroll
    for (int it = 0; it < 2; it++) {
        int idx = threadIdx.x + it * 256;
        int sl = idx >> 3, dg = (idx & 7) * 8;
        *(uintx4*)&t[sl * 72 + dg] = *(const uintx4*)&v[((size_t)bh * S_ + s0 + sl) * HD_ + dg];
    }
    __syncthreads();
    #pragma unroll
    for (int it = 0; it < 2; it++) {
        int idx = threadIdx.x + it * 256;
        int dl = idx >> 3, sg = (idx & 7) * 8;
        ushortx8 o;
        #pragma unroll
        for (int i = 0; i < 8; i++) o[i] = f2h(bf2f(t[(sg + i) * 72 + dl]));
        *(ushortx8*)&vT[((size_t)bh * HD_ + dl) * S_ + s0 + sg] = o;
    }
}

// ---------------------------------------------------------------- GEMM: C = A(M,K) @ BT(N,K)^T + bias
// ep: 0 = bf16 row-major out ; 1 = + exact GELU ; 2 = fused QKV -> (3,B,H,S,HD)
__global__ __launch_bounds__(256) void gemm_bt(const ushort_t* __restrict__ A,
                                               const ushort_t* __restrict__ BT,
                                               const float* __restrict__ bias,
                                               ushort_t* __restrict__ C,
                                               int M, int N, int K, int ep) {
    __shared__ ushort_t As[128 * 32];   // unpadded: required by global_load_lds lane mapping
    __shared__ ushort_t Bs[128 * 32];

    const int tid = threadIdx.x;
    const int wid = tid >> 6, lane = tid & 63;
    const int quad = lane >> 4, r = lane & 15;
    const int wr = wid >> 1, wc = wid & 1;
    const int m0 = blockIdx.y * 128, n0 = blockIdx.x * 128;

    floatx4 acc[4][4];
    #pragma unroll
    for (int a = 0; a < 4; a++)
        #pragma unroll
        for (int b = 0; b < 4; b++) acc[a][b] = (floatx4){0.f, 0.f, 0.f, 0.f};

    // staging map: wave wid covers 16 rows/call; lane -> (row=lane>>2, col8=(lane&3)*8)
    const int srow = wid * 16 + (lane >> 2);
    const int scol = (lane & 3) * 8;
    const ushort_t* Ag0 = A + (size_t)(m0 + srow) * K + scol;
    const ushort_t* Ag1 = A + (size_t)(m0 + 64 + srow) * K + scol;
    const ushort_t* Bg0 = BT + (size_t)(n0 + srow) * K + scol;
    const ushort_t* Bg1 = BT + (size_t)(n0 + 64 + srow) * K + scol;
    ushort_t* Asd0 = As + (wid * 16) * 32;
    ushort_t* Asd1 = As + (64 + wid * 16) * 32;
    ushort_t* Bsd0 = Bs + (wid * 16) * 32;
    ushort_t* Bsd1 = Bs + (64 + wid * 16) * 32;

    for (int k0 = 0; k0 < K; k0 += 32) {
        __syncthreads();
        gload_lds16(Ag0 + k0, Asd0);
        gload_lds16(Ag1 + k0, Asd1);
        gload_lds16(Bg0 + k0, Bsd0);
        gload_lds16(Bg1 + k0, Bsd1);
        __syncthreads();

        short8 af[4], bf[4];
        #pragma unroll
        for (int t = 0; t < 4; t++)
            af[t] = *(const short8*)&As[(wr * 64 + t * 16 + r) * 32 + quad * 8];
        #pragma unroll
        for (int t = 0; t < 4; t++)
            bf[t] = *(const short8*)&Bs[(wc * 64 + t * 16 + r) * 32 + quad * 8];
        #pragma unroll
        for (int tm = 0; tm < 4; tm++)
            #pragma unroll
            for (int tn = 0; tn < 4; tn++)
                acc[tm][tn] = __builtin_amdgcn_mfma_f32_16x16x32_bf16(af[tm], bf[tn], acc[tm][tn], 0, 0, 0);
    }

    #pragma unroll
    for (int tm = 0; tm < 4; tm++) {
        #pragma unroll
        for (int tn = 0; tn < 4; tn++) {
            const int n = n0 + wc * 64 + tn * 16 + r;      // C col = lane&15 (m89-verified)
            const float bv = bias[n];
            #pragma unroll
            for (int i2 = 0; i2 < 4; i2++) {
                const int m = m0 + wr * 64 + tm * 16 + quad * 4 + i2;  // row = quad*4+reg
                float v = acc[tm][tn][i2] + bv;
                if (ep == 1) v = 0.5f * v * (1.0f + erff(v * 0.70710678118654752f));
                size_t idx;
                if (ep == 2) {
                    // (b,s) x (tensor,h,d) -> tensor*(B,H,S,HD)
                    int tensor = n >> 10, nn = n & 1023;
                    idx = (size_t)tensor * (B_ * S_ * D_)
                        + (((size_t)(m >> 10) * H_ + (nn >> 6)) * S_ + (m & (S_ - 1))) * HD_ + (nn & (HD_ - 1));
                } else {
                    idx = (size_t)m * N + n;
                }
                C[idx] = f2bf(v);
            }
        }
    }
}

// ---------------------------------------------------------------- fused attention (per b,h,16-query tile)
// LDS: scores only, 16 rows x 1024 fp16 = 32768 B exact -> 5 blocks/CU (was 4).
// Score rows are XOR-block-swizzled: within row, 16B block L holds col-block L ^ (row&7).
//  - staging: linear LDS dest (global_load_lds requirement) + pre-swizzled global source
//  - QK^T scalar read/write, select b128 read/write, PV b128 read all apply the same XOR
//  - keeps PV ds_read at the 8-cycle b128 minimum despite the now power-of-2 row stride
__global__ __launch_bounds__(256) void attn_kernel(const ushort_t* __restrict__ q,
                                                   const ushort_t* __restrict__ k,
                                                   const ushort_t* __restrict__ vT,
                                                   const ushort_t* __restrict__ biasb,
                                                   ushort_t* __restrict__ attnb) {
    extern __shared__ char smem[];
    ushort_t* Sm = (ushort_t*)smem;                 // 16 x 1024 fp16, swizzled
    _Float16* Smh = (_Float16*)smem;

    const int bid = blockIdx.x;
    const int b = bid >> 10;
    const int h = (bid >> 6) & (H_ - 1);
    const int i0 = (bid & 63) * 16;
    const int tid = threadIdx.x;
    const int wid = tid >> 6, lane = tid & 63;
    const int quad = lane >> 4, r = lane & 15;

    const size_t bh = (size_t)b * H_ + h;
    const ushort_t* qbase = q + bh * S_ * HD_;
    const ushort_t* kbase = k + bh * S_ * HD_;
    const ushort_t* vbase = vT + bh * HD_ * S_;
    const ushort_t* bsrc = biasb + ((size_t)b * S_ + i0) * S_;  // 16 rows, contiguous 32KB

    // stage bias fp16 via async global->LDS: 32 chunks of 1KB.
    // LDS dest linear; source lane index pre-swizzled (lane ^ (row&7)) so that
    // in-row block L ends up holding col-block L ^ (row&7).
    #pragma unroll
    for (int c8 = 0; c8 < 8; c8++) {
        int c = wid * 8 + c8;
        int row = c >> 1, half = c & 1;
        int xr = row & 7;
        gload_lds16(bsrc + (size_t)row * S_ + half * 512 + (lane ^ xr) * 8,
                    Sm + row * 1024 + half * 512);
    }
    // q fragments straight from global (pure per-lane loads; L1/L2-hit, 4x wave redundancy is free)
    short8 aq0 = *(const short8*)&qbase[(size_t)(i0 + r) * HD_ + quad * 8];
    short8 aq1 = *(const short8*)&qbase[(size_t)(i0 + r) * HD_ + 32 + quad * 8];
    __syncthreads();

    // ---- QK^T: score = q*K^T + bias (0.125 scale pre-folded into Wq/bq); acc init from bias
    #pragma unroll 4
    for (int t = 0; t < 16; t++) {
        int jt = (t * 4 + wid) * 16;
        int cb = (jt + r) >> 3;        // col 16B-block
        int co = r & 7;                // offset within block
        floatx4 acc;
        int la[4];
        #pragma unroll
        for (int i2 = 0; i2 < 4; i2++) {
            int row = quad * 4 + i2;
            la[i2] = row * 1024 + ((cb ^ (row & 7)) << 3) + co;
            acc[i2] = (float)Smh[la[i2]];
        }
        const ushort_t* kp = kbase + (size_t)(jt + r) * HD_ + quad * 8;  // B[k][n=lane&15] = K[n][k]
        short8 b0 = *(const short8*)kp;
        short8 b1 = *(const short8*)(kp + 32);
        acc = __builtin_amdgcn_mfma_f32_16x16x32_bf16(aq0, b0, acc, 0, 0, 0);
        acc = __builtin_amdgcn_mfma_f32_16x16x32_bf16(aq1, b1, acc, 0, 0, 0);
        #pragma unroll
        for (int i2 = 0; i2 < 4; i2++)
            Smh[la[i2]] = (_Float16)acc[i2];
    }
    __syncthreads();

    // ---- exact top-64 on fp16 scores: 16-bit radix select, ballot-counted.
    // Lane owns LDS blocks {lane, 64+lane} of its row (conflict-free b128, banks lane&7).
    // Search-space shrink: K64 lies in [T0, M] where T0 = min over lanes of per-lane max key
    //   (the 64 per-lane maxima are 64 elements => count(>=T0) >= 64) and M = row max key.
    //   Start from their common prefix; early-exit when count == 64 (selected set proven equal).
    for (int rr = 0; rr < 4; rr++) {
        int row = wid * 4 + rr;
        ushort_t* Srow = Sm + row * 1024;
        ushortx8 u0 = *(const ushortx8*)&Srow[lane * 8];
        ushortx8 u1 = *(const ushortx8*)&Srow[(64 + lane) * 8];
        unsigned int kk[16];
        unsigned int lmax = 0u;
        #pragma unroll
        for (int t = 0; t < 8; t++) {
            unsigned int ua = u0[t];
            kk[t] = ua ^ ((ua & 0x8000u) ? 0xFFFFu : 0x8000u);   // order-preserving key map
            lmax = kk[t] > lmax ? kk[t] : lmax;
            unsigned int ub = u1[t];
            kk[8 + t] = ub ^ ((ub & 0x8000u) ? 0xFFFFu : 0x8000u);
            lmax = kk[8 + t] > lmax ? kk[8 + t] : lmax;
        }
        unsigned int M = lmax, T0 = lmax;
        #pragma unroll
        for (int off = 32; off; off >>= 1) {
            unsigned int om = (unsigned int)__shfl_xor((int)M, off);
            unsigned int ot = (unsigned int)__shfl_xor((int)T0, off);
            M = om > M ? om : M;
            T0 = ot < T0 ? ot : T0;
        }
        // row max value (for exp stabilization) from inverse key map
        float mx = h2f((ushort_t)((M & 0x8000u) ? (M ^ 0x8000u) : (~M & 0xFFFFu)));
        unsigned int T;
        int hb;
        unsigned int diff = T0 ^ M;
        if (diff == 0u) { T = M; hb = -1; }
        else { hb = 31 - __builtin_clz(diff); T = M & ~((2u << hb) - 1u); }
        for (int bit = hb; bit >= 0; bit--) {
            unsigned int trial = T | (1u << bit);
            int c = 0;
            #pragma unroll
            for (int t = 0; t < 16; t++)
                c += __popcll(__ballot(kk[t] >= trial));
            if (c >= KTOP) {
                T = trial;
                if (c == KTOP) break;   // selected set already unique == top-64
            }
        }
        float ev[16]; float sum = 0.f;
        #pragma unroll
        for (int t = 0; t < 8; t++) {
            float sa = h2f((ushort_t)u0[t]);
            float ea = (kk[t] >= T) ? __expf(sa - mx) : 0.f;     // ties kept (matches >= kth)
            ev[t] = ea; sum += ea;
            float sb = h2f((ushort_t)u1[t]);
            float eb = (kk[8 + t] >= T) ? __expf(sb - mx) : 0.f;
            ev[8 + t] = eb; sum += eb;
        }
        #pragma unroll
        for (int off = 32; off; off >>= 1) sum += __shfl_xor(sum, off);
        float inv = 1.f / sum;
        ushortx8 w0, w1;
        #pragma unroll
        for (int t = 0; t < 8; t++) {
            w0[t] = f2h(ev[t] * inv);
            w1[t] = f2h(ev[8 + t] * inv);
        }
        *(ushortx8*)&Srow[lane * 8] = w0;
        *(ushortx8*)&Srow[(64 + lane) * 8] = w1;
    }
    __syncthreads();

    // ---- PV (f16 MFMA): attn(16 x 64) = W(16 x 1024) @ V(1024 x 64); wave wid owns d-tile wid*16
    // Two accumulators break the 32-long serial MFMA dependence chain.
    floatx4 o0 = (floatx4){0.f, 0.f, 0.f, 0.f};
    floatx4 o1 = (floatx4){0.f, 0.f, 0.f, 0.f};
    const _Float16* Srowp = Smh + (size_t)r * 1024;
    const int xr = r & 7;
    const ushort_t* vrow = vbase + (size_t)(wid * 16 + r) * S_;
    #pragma unroll 4
    for (int ks2 = 0; ks2 < 16; ks2++) {
        int ks = ks2 * 2;
        half8 wa0 = *(const half8*)&Srowp[((ks * 4 + quad) ^ xr) << 3];
        half8 wa1 = *(const half8*)&Srowp[(((ks + 1) * 4 + quad) ^ xr) << 3];
        half8 vb0 = *(const half8*)&vrow[ks * 32 + quad * 8];
        half8 vb1 = *(const half8*)&vrow[(ks + 1) * 32 + quad * 8];
        o0 = __builtin_amdgcn_mfma_f32_16x16x32_f16(wa0, vb0, o0, 0, 0, 0);
        o1 = __builtin_amdgcn_mfma_f32_16x16x32_f16(wa1, vb1, o1, 0, 0, 0);
    }
    floatx4 oacc = o0 + o1;
    #pragma unroll
    for (int i2 = 0; i2 < 4; i2++) {
        int row = quad * 4 + i2;
        attnb[((size_t)b * S_ + i0 + row) * D_ + h * HD_ + wid * 16 + r] = f2bf(oacc[i2]);
    }
}

// ---------------------------------------------------------------- layernorm kernels
__global__ __launch_bounds__(256) void ln1_kernel(const float* __restrict__ x,
                                                  const ushort_t* __restrict__ t,
                                                  const float* __restrict__ g,
                                                  const float* __restrict__ be,
                                                  ushort_t* __restrict__ hb) {
    int row = blockIdx.x, tid = threadIdx.x;
    const float* xr = x + (size_t)row * D_;
    const ushort_t* tr = t + (size_t)row * D_;
    float v[4]; float s = 0.f, s2 = 0.f;
    #pragma unroll
    for (int it = 0; it < 4; it++) {
        int j = tid + it * 256;
        v[it] = xr[j] + bf2f(tr[j]);
        s += v[it]; s2 += v[it] * v[it];
    }
    #pragma unroll
    for (int off = 32; off; off >>= 1) { s += __shfl_xor(s, off); s2 += __shfl_xor(s2, off); }
    __shared__ float rs[4], rq[4];
    if ((tid & 63) == 0) { rs[tid >> 6] = s; rq[tid >> 6] = s2; }
    __syncthreads();
    s = rs[0] + rs[1] + rs[2] + rs[3];
    s2 = rq[0] + rq[1] + rq[2] + rq[3];
    float mu = s * (1.f / D_);
    float var = s2 * (1.f / D_) - mu * mu;
    float rstd = rsqrtf(var + 1e-5f);
    #pragma unroll
    for (int it = 0; it < 4; it++) {
        int j = tid + it * 256;
        hb[(size_t)row * D_ + j] = f2bf((v[it] - mu) * rstd * g[j] + be[j]);
    }
}

__global__ __launch_bounds__(256) void ln2_kernel(const ushort_t* __restrict__ hbuf,
                                                  const ushort_t* __restrict__ t,
                                                  const float* __restrict__ g,
                                                  const float* __restrict__ be,
                                                  float* __restrict__ out) {
    int row = blockIdx.x, tid = threadIdx.x;
    const ushort_t* hr = hbuf + (size_t)row * D_;
    const ushort_t* tr = t + (size_t)row * D_;
    float v[4]; float s = 0.f, s2 = 0.f;
    #pragma unroll
    for (int it = 0; it < 4; it++) {
        int j = tid + it * 256;
        v[it] = bf2f(hr[j]) + bf2f(tr[j]);
        s += v[it]; s2 += v[it] * v[it];
    }
    #pragma unroll
    for (int off = 32; off; off >>= 1) { s += __shfl_xor(s, off); s2 += __shfl_xor(s2, off); }
    __shared__ float rs[4], rq[4];
    if ((tid & 63) == 0) { rs[tid >> 6] = s; rq[tid >> 6] = s2; }
    __syncthreads();
    s = rs[0] + rs[1] + rs[2] + rs[3];
    s2 = rq[0] + rq[1] + rq[2] + rq[3];
    float mu = s * (1.f / D_);
    float var = s2 * (1.f / D_) - mu * mu;
    float rstd = rsqrtf(var + 1e-5f);
    #pragma unroll
    for (int it = 0; it < 4; it++) {
        int j = tid + it * 256;
        out[(size_t)row * D_ + j] = (v[it] - mu) * rstd * g[j] + be[j];
    }
}

// ---------------------------------------------------------------- launch
extern "C" void kernel_launch(void* const* d_in, const int* in_sizes, int n_in,
                              void* d_out, int out_size, void* d_ws, size_t ws_size,
                              hipStream_t stream) {
    (void)in_sizes; (void)n_in; (void)out_size; (void)ws_size;
    const float* x   = (const float*)d_in[0];
    const int*   tok = (const int*)d_in[1];
    const float* pmi = (const float*)d_in[2];
    const float* Wq  = (const float*)d_in[3];
    const float* bq  = (const float*)d_in[4];
    const float* Wk  = (const float*)d_in[5];
    const float* bk  = (const float*)d_in[6];
    const float* Wv  = (const float*)d_in[7];
    const float* bv  = (const float*)d_in[8];
    const float* Wo  = (const float*)d_in[9];
    const float* bo  = (const float*)d_in[10];
    const float* W1  = (const float*)d_in[11];
    const float* b1  = (const float*)d_in[12];
    const float* W2  = (const float*)d_in[13];
    const float* b2  = (const float*)d_in[14];
    const float* g1  = (const float*)d_in[15];
    const float* be1 = (const float*)d_in[16];
    const float* g2  = (const float*)d_in[17];
    const float* be2 = (const float*)d_in[18];
    float* out = (float*)d_out;

    char* ws = (char*)d_ws;
    size_t off = 0;
    auto alloc = [&](size_t bytes) { char* p = ws + off; off += (bytes + 255) & ~(size_t)255; return p; };
    const size_t BSD = (size_t)B_ * S_ * D_;
    ushort_t* xb     = (ushort_t*)alloc(BSD * 2);                 // 16.8 MB
    ushort_t* WqkvT  = (ushort_t*)alloc((size_t)3 * D_ * D_ * 2); // 6 MB (q,k,v contiguous)
    ushort_t* WoT    = (ushort_t*)alloc((size_t)D_ * D_ * 2);
    ushort_t* W1T    = (ushort_t*)alloc((size_t)D_ * F_ * 2);
    ushort_t* W2T    = (ushort_t*)alloc((size_t)F_ * D_ * 2);
    float*    bqkv   = (float*)alloc(3072 * 4);
    ushort_t* qkvb   = (ushort_t*)alloc(3 * BSD * 2);             // 50 MB (q,k,v)
    ushort_t* vT     = (ushort_t*)alloc(BSD * 2);
    ushort_t* biasb  = (ushort_t*)alloc((size_t)B_ * S_ * S_ * 2);
    ushort_t* extra  = (ushort_t*)alloc(BSD * 2);
    (void)extra;
    // aliases (strict stream-order reuse)
    ushort_t* qb    = qkvb;
    ushort_t* kb    = qkvb + BSD;
    ushort_t* vb    = qkvb + 2 * BSD;
    ushort_t* attnb = xb;           // xb dead after QKV GEMM
    ushort_t* tbuf  = qb;           // q dead after attention
    ushort_t* hb    = kb;           // k dead after attention
    ushort_t* ffb   = vb;           // v+vT+biasb+extra (64MB contiguous) dead after attention

    const size_t attn_lds = 16 * 1024 * 2;                     // 32768 B exact -> 5 blocks/CU

    cast_x_kernel<<<8192, 256, 0, stream>>>(x, xb);
    transpose_cast_kernel<<<dim3(32, 32), dim3(32, 8), 0, stream>>>(Wq, WqkvT, D_, D_, 0.125f);
    transpose_cast_kernel<<<dim3(32, 32), dim3(32, 8), 0, stream>>>(Wk, WqkvT + (size_t)D_ * D_, D_, D_, 1.0f);
    transpose_cast_kernel<<<dim3(32, 32), dim3(32, 8), 0, stream>>>(Wv, WqkvT + (size_t)2 * D_ * D_, D_, D_, 1.0f);
    transpose_cast_kernel<<<dim3(32, 32), dim3(32, 8), 0, stream>>>(Wo, WoT, D_, D_, 1.0f);
    transpose_cast_kernel<<<dim3(128, 32), dim3(32, 8), 0, stream>>>(W1, W1T, D_, F_, 1.0f);
    transpose_cast_kernel<<<dim3(32, 128), dim3(32, 8), 0, stream>>>(W2, W2T, F_, D_, 1.0f);
    pack_bias3_kernel<<<12, 256, 0, stream>>>(bq, bk, bv, bqkv);
    bias_gather_kernel<<<B_ * S_, 256, 0, stream>>>(tok, pmi, biasb);

    gemm_bt<<<dim3(24, 64), 256, 0, stream>>>(xb, WqkvT, bqkv, qkvb, B_ * S_, 3 * D_, D_, 2);
    transpose_v_kernel<<<B_ * H_ * (S_ / 64), 256, 0, stream>>>(vb, vT);

    attn_kernel<<<B_ * H_ * (S_ / 16), 256, attn_lds, stream>>>(qb, kb, vT, biasb, attnb);

    gemm_bt<<<dim3(8, 64), 256, 0, stream>>>(attnb, WoT, bo, tbuf, B_ * S_, D_, D_, 0);
    ln1_kernel<<<B_ * S_, 256, 0, stream>>>(x, tbuf, g1, be1, hb);
    gemm_bt<<<dim3(32, 64), 256, 0, stream>>>(hb, W1T, b1, ffb, B_ * S_, F_, D_, 1);
    gemm_bt<<<dim3(8, 64), 256, 0, stream>>>(ffb, W2T, b2, tbuf, B_ * S_, D_, F_, 0);
    ln2_kernel<<<B_ * S_, 256, 0, stream>>>(hb, tbuf, g2, be2, out);
}

// Round 2
// 1099.659 us; speedup vs baseline: 1.0721x; 1.0439x over previous
//
#include <hip/hip_runtime.h>
#include <cstdint>
#include <cstddef>

// Problem constants
#define B_   8
#define S_   1024
#define D_   1024
#define H_   16
#define HD_  64
#define F_   4096
#define V_   8192
#define KTOP 64

typedef unsigned short ushort_t;
typedef __attribute__((ext_vector_type(8))) short short8;            // MFMA bf16 A/B frag (4 VGPR)
typedef __attribute__((ext_vector_type(8))) _Float16 half8;          // MFMA f16 A/B frag
typedef __attribute__((ext_vector_type(4))) float floatx4;           // MFMA C/D frag
typedef __attribute__((ext_vector_type(4))) unsigned int uintx4;     // 16B copy
typedef __attribute__((ext_vector_type(4))) float floatv4;
typedef __attribute__((ext_vector_type(4))) unsigned short ushortx4;
typedef __attribute__((ext_vector_type(8))) unsigned short ushortx8;

__device__ __forceinline__ ushort_t f2bf(float f) {
    unsigned int u = __builtin_bit_cast(unsigned int, f);
    u += 0x7fffu + ((u >> 16) & 1u);            // round-to-nearest-even
    return (ushort_t)(u >> 16);
}
__device__ __forceinline__ float bf2f(ushort_t u) {
    unsigned int x = ((unsigned int)u) << 16;
    return __builtin_bit_cast(float, x);
}
__device__ __forceinline__ ushort_t f2h(float f) {
    _Float16 h = (_Float16)f;
    return __builtin_bit_cast(ushort_t, h);
}
__device__ __forceinline__ float h2f(ushort_t u) {
    return (float)__builtin_bit_cast(_Float16, u);
}

// async global->LDS, 16B per lane; lds dest = wave-uniform base + lane*16
__device__ __forceinline__ void gload_lds16(const ushort_t* g, ushort_t* lds_base) {
    __builtin_amdgcn_global_load_lds(
        (const __attribute__((address_space(1))) unsigned int*)g,
        (__attribute__((address_space(3))) unsigned int*)lds_base,
        16, 0, 0);
}

// ---------------------------------------------------------------- cast x -> bf16
__global__ __launch_bounds__(256) void cast_x_kernel(const float* __restrict__ x,
                                                     ushort_t* __restrict__ xb) {
    int gid = blockIdx.x * 256 + threadIdx.x;   // 4 elems per thread
    floatv4 v = ((const floatv4*)x)[gid];
    ushortx4 o;
    o[0] = f2bf(v[0]); o[1] = f2bf(v[1]); o[2] = f2bf(v[2]); o[3] = f2bf(v[3]);
    ((ushortx4*)xb)[gid] = o;
}

// ------------------------------------------- transpose + cast weight: W(K,N) -> WT(N,K) bf16, * scale
__global__ void transpose_cast_kernel(const float* __restrict__ W, ushort_t* __restrict__ WT,
                                      int K, int N, float scale) {
    __shared__ float tile[32][33];
    int n0 = blockIdx.x * 32, k0 = blockIdx.y * 32;
    #pragma unroll
    for (int i = threadIdx.y; i < 32; i += 8)
        tile[i][threadIdx.x] = W[(size_t)(k0 + i) * N + n0 + threadIdx.x];
    __syncthreads();
    #pragma unroll
    for (int i = threadIdx.y; i < 32; i += 8)
        WT[(size_t)(n0 + i) * K + k0 + threadIdx.x] = f2bf(tile[threadIdx.x][i] * scale);
}

// ---------------------------------------------------------------- pack q/k/v biases (bq scaled 1/8)
__global__ __launch_bounds__(256) void pack_bias3_kernel(const float* __restrict__ bq,
                                                         const float* __restrict__ bk,
                                                         const float* __restrict__ bv,
                                                         float* __restrict__ o) {
    int i = blockIdx.x * 256 + threadIdx.x;   // 3072 total
    float v = (i < 1024) ? bq[i] * 0.125f : (i < 2048) ? bk[i - 1024] : bv[i - 2048];
    o[i] = v;
}

// ---------------------------------------------------------------- pmi bias gather -> fp16 (ALPHA folded)
__global__ __launch_bounds__(256) void bias_gather_kernel(const int* __restrict__ tok,
                                                          const float* __restrict__ pmi,
                                                          ushort_t* __restrict__ biasb) {
    int b = blockIdx.x >> 10;
    int i = blockIdx.x & (S_ - 1);
    int ti = tok[b * S_ + i];
    const float* prow = pmi + (size_t)ti * V_;
    #pragma unroll
    for (int it = 0; it < 4; it++) {
        int j = threadIdx.x + it * 256;
        int tj = tok[b * S_ + j];
        biasb[(size_t)blockIdx.x * S_ + j] = f2h(0.1f * prow[tj]);
    }
}

// ---------------------------------------------------------------- V (B,H,S,HD) bf16 -> vT (B,H,HD,S) fp16
__global__ __launch_bounds__(256) void transpose_v_kernel(const ushort_t* __restrict__ v,
                                                          ushort_t* __restrict__ vT) {
    __shared__ ushort_t t[64 * 72];   // [s_loc][d], stride 72
    int bh = blockIdx.x >> 4;
    int s0 = (blockIdx.x & 15) * 64;
    #pragma unroll
    for (int it = 0; it < 2; it++) {
        int idx = threadIdx.x + it * 256;
        int sl = idx >> 3, dg = (idx & 7) * 8;
        *(uintx4*)&t[sl * 72 + dg] = *(const uintx4*)&v[((size_t)bh * S_ + s0 + sl) * HD_ + dg];
    }
    __syncthreads();
    #pragma unroll
    for (int it = 0; it < 2; it++) {
        int idx = threadIdx.x + it * 256;
        int dl = idx >> 3, sg = (idx & 7) * 8;
        ushortx8 o;
        #pragma unroll
        for (int i = 0; i < 8; i++) o[i] = f2h(bf2f(t[(sg + i) * 72 + dl]));
        *(ushortx8*)&vT[((size_t)bh * HD_ + dl) * S_ + s0 + sg] = o;
    }
}

// ---------------------------------------------------------------- GEMM: C = A(M,K) @ BT(N,K)^T + bias
// T3 minimum-2-phase: double-buffered LDS, prefetch tile t+1 issued BEFORE compute of
// tile t, single barrier per K-step (syncthreads drains vmcnt+lgkm => race-free).
// ep: 0 = bf16 row-major out ; 1 = + exact GELU ; 2 = fused QKV -> (3,B,H,S,HD)
__global__ __launch_bounds__(256) void gemm_bt(const ushort_t* __restrict__ A,
                                               const ushort_t* __restrict__ BT,
                                               const float* __restrict__ bias,
                                               ushort_t* __restrict__ C,
                                               int M, int N, int K, int ep) {
    __shared__ ushort_t As[2][128 * 32];   // unpadded: required by global_load_lds lane mapping
    __shared__ ushort_t Bs[2][128 * 32];

    const int tid = threadIdx.x;
    const int wid = tid >> 6, lane = tid & 63;
    const int quad = lane >> 4, r = lane & 15;
    const int wr = wid >> 1, wc = wid & 1;
    const int m0 = blockIdx.y * 128, n0 = blockIdx.x * 128;

    floatx4 acc[4][4];
    #pragma unroll
    for (int a = 0; a < 4; a++)
        #pragma unroll
        for (int b = 0; b < 4; b++) acc[a][b] = (floatx4){0.f, 0.f, 0.f, 0.f};

    // staging map: wave wid covers 16 rows/call; lane -> (row=lane>>2, col8=(lane&3)*8)
    const int srow = wid * 16 + (lane >> 2);
    const int scol = (lane & 3) * 8;
    const ushort_t* Ag0 = A + (size_t)(m0 + srow) * K + scol;
    const ushort_t* Ag1 = A + (size_t)(m0 + 64 + srow) * K + scol;
    const ushort_t* Bg0 = BT + (size_t)(n0 + srow) * K + scol;
    const ushort_t* Bg1 = BT + (size_t)(n0 + 64 + srow) * K + scol;
    const int d0 = (wid * 16) * 32;
    const int d1 = (64 + wid * 16) * 32;

    // prologue: stage K-tile 0 into buffer 0
    gload_lds16(Ag0, &As[0][d0]);
    gload_lds16(Ag1, &As[0][d1]);
    gload_lds16(Bg0, &Bs[0][d0]);
    gload_lds16(Bg1, &Bs[0][d1]);
    __syncthreads();

    int cur = 0;
    for (int k0 = 0; k0 < K; k0 += 32) {
        const int nxt = cur ^ 1;
        if (k0 + 32 < K) {      // issue next-tile prefetch FIRST; hides under MFMA below
            gload_lds16(Ag0 + k0 + 32, &As[nxt][d0]);
            gload_lds16(Ag1 + k0 + 32, &As[nxt][d1]);
            gload_lds16(Bg0 + k0 + 32, &Bs[nxt][d0]);
            gload_lds16(Bg1 + k0 + 32, &Bs[nxt][d1]);
        }
        short8 af[4], bf[4];
        #pragma unroll
        for (int t = 0; t < 4; t++)
            af[t] = *(const short8*)&As[cur][(wr * 64 + t * 16 + r) * 32 + quad * 8];
        #pragma unroll
        for (int t = 0; t < 4; t++)
            bf[t] = *(const short8*)&Bs[cur][(wc * 64 + t * 16 + r) * 32 + quad * 8];
        #pragma unroll
        for (int tm = 0; tm < 4; tm++)
            #pragma unroll
            for (int tn = 0; tn < 4; tn++)
                acc[tm][tn] = __builtin_amdgcn_mfma_f32_16x16x32_bf16(af[tm], bf[tn], acc[tm][tn], 0, 0, 0);
        __syncthreads();        // drains prefetch (vmcnt0) + ds_reads (lgkm0), then barrier
        cur = nxt;
    }

    #pragma unroll
    for (int tm = 0; tm < 4; tm++) {
        #pragma unroll
        for (int tn = 0; tn < 4; tn++) {
            const int n = n0 + wc * 64 + tn * 16 + r;      // C col = lane&15 (m89-verified)
            const float bv = bias[n];
            #pragma unroll
            for (int i2 = 0; i2 < 4; i2++) {
                const int m = m0 + wr * 64 + tm * 16 + quad * 4 + i2;  // row = quad*4+reg
                float v = acc[tm][tn][i2] + bv;
                if (ep == 1) v = 0.5f * v * (1.0f + erff(v * 0.70710678118654752f));
                size_t idx;
                if (ep == 2) {
                    // (b,s) x (tensor,h,d) -> tensor*(B,H,S,HD)
                    int tensor = n >> 10, nn = n & 1023;
                    idx = (size_t)tensor * (B_ * S_ * D_)
                        + (((size_t)(m >> 10) * H_ + (nn >> 6)) * S_ + (m & (S_ - 1))) * HD_ + (nn & (HD_ - 1));
                } else {
                    idx = (size_t)m * N + n;
                }
                C[idx] = f2bf(v);
            }
        }
    }
}

// ---------------------------------------------------------------- fused attention (per b,h,16-query tile)
// LDS: scores only, 16 rows x 1024 fp16 = 32768 B, XOR-block-swizzled (block L holds col-block L^(row&7)).
// QK^T computes the TRANSPOSED tile via mfma(K_frag, Q_frag): operand loads identical, but a lane
// then holds 4 CONSECUTIVE KEYS of ONE query row -> bias-init is one ds_read_b64 and score
// write-back one ds_write_b64 (vs 4 scalar u16 each). Select and PV layouts unchanged.
__global__ __launch_bounds__(256) void attn_kernel(const ushort_t* __restrict__ q,
                                                   const ushort_t* __restrict__ k,
                                                   const ushort_t* __restrict__ vT,
                                                   const ushort_t* __restrict__ biasb,
                                                   ushort_t* __restrict__ attnb) {
    extern __shared__ char smem[];
    ushort_t* Sm = (ushort_t*)smem;                 // 16 x 1024 fp16, swizzled
    _Float16* Smh = (_Float16*)smem;

    const int bid = blockIdx.x;
    const int b = bid >> 10;
    const int h = (bid >> 6) & (H_ - 1);
    const int i0 = (bid & 63) * 16;
    const int tid = threadIdx.x;
    const int wid = tid >> 6, lane = tid & 63;
    const int quad = lane >> 4, r = lane & 15;

    const size_t bh = (size_t)b * H_ + h;
    const ushort_t* qbase = q + bh * S_ * HD_;
    const ushort_t* kbase = k + bh * S_ * HD_;
    const ushort_t* vbase = vT + bh * HD_ * S_;
    const ushort_t* bsrc = biasb + ((size_t)b * S_ + i0) * S_;  // 16 rows, contiguous 32KB

    // stage bias fp16 via async global->LDS: 32 chunks of 1KB.
    // LDS dest linear; source lane index pre-swizzled (lane ^ (row&7)) so that
    // in-row block L ends up holding col-block L ^ (row&7).
    #pragma unroll
    for (int c8 = 0; c8 < 8; c8++) {
        int c = wid * 8 + c8;
        int row = c >> 1, half = c & 1;
        int xr = row & 7;
        gload_lds16(bsrc + (size_t)row * S_ + half * 512 + (lane ^ xr) * 8,
                    Sm + row * 1024 + half * 512);
    }
    // q fragments straight from global (pure per-lane loads; L1/L2-hit, 4x wave redundancy is free)
    short8 aq0 = *(const short8*)&qbase[(size_t)(i0 + r) * HD_ + quad * 8];
    short8 aq1 = *(const short8*)&qbase[(size_t)(i0 + r) * HD_ + 32 + quad * 8];
    __syncthreads();

    // ---- QK^T (swapped operands): S^T tile = K_frag * Q_frag.
    // D[m=key_sub][n=query]: col=lane&15=r -> query r; rows quad*4+i2 -> keys jt+quad*4+{0..3}.
    // LDS addr: 4 consecutive fp16 of row r at col jt+quad*4; 16B-block cb = 8t + 2*wid + (quad>>1)
    // => swizzled element addr la = labase + 64*t (one b64 read + one b64 write per iter).
    const int low3 = 2 * wid + (quad >> 1);
    const int labase = r * 1024 + ((low3 ^ (r & 7)) << 3) + (quad & 1) * 4;
    const ushort_t* kpl = kbase + (size_t)(wid * 16 + r) * HD_ + quad * 8;
    #pragma unroll 4
    for (int t = 0; t < 16; t++) {
        const int la = labase + t * 64;
        ushortx4 bi = *(const ushortx4*)&Sm[la];
        floatx4 acc;
        acc[0] = h2f(bi[0]); acc[1] = h2f(bi[1]); acc[2] = h2f(bi[2]); acc[3] = h2f(bi[3]);
        const ushort_t* kp = kpl + (size_t)t * 64 * HD_;
        short8 b0 = *(const short8*)kp;
        short8 b1 = *(const short8*)(kp + 32);
        acc = __builtin_amdgcn_mfma_f32_16x16x32_bf16(b0, aq0, acc, 0, 0, 0);
        acc = __builtin_amdgcn_mfma_f32_16x16x32_bf16(b1, aq1, acc, 0, 0, 0);
        ushortx4 so;
        so[0] = f2h(acc[0]); so[1] = f2h(acc[1]); so[2] = f2h(acc[2]); so[3] = f2h(acc[3]);
        *(ushortx4*)&Sm[la] = so;
    }
    __syncthreads();

    // ---- exact top-64 on fp16 scores: 16-bit radix select, ballot-counted.
    // Lane owns LDS blocks {lane, 64+lane} of its row (conflict-free b128, banks lane&7).
    // Search-space shrink: K64 lies in [T0, M] where T0 = min over lanes of per-lane max key
    //   (the 64 per-lane maxima are 64 elements => count(>=T0) >= 64) and M = row max key.
    //   Start from their common prefix; early-exit when count == 64 (selected set proven equal).
    for (int rr = 0; rr < 4; rr++) {
        int row = wid * 4 + rr;
        ushort_t* Srow = Sm + row * 1024;
        ushortx8 u0 = *(const ushortx8*)&Srow[lane * 8];
        ushortx8 u1 = *(const ushortx8*)&Srow[(64 + lane) * 8];
        unsigned int kk[16];
        unsigned int lmax = 0u;
        #pragma unroll
        for (int t = 0; t < 8; t++) {
            unsigned int ua = u0[t];
            kk[t] = ua ^ ((ua & 0x8000u) ? 0xFFFFu : 0x8000u);   // order-preserving key map
            lmax = kk[t] > lmax ? kk[t] : lmax;
            unsigned int ub = u1[t];
            kk[8 + t] = ub ^ ((ub & 0x8000u) ? 0xFFFFu : 0x8000u);
            lmax = kk[8 + t] > lmax ? kk[8 + t] : lmax;
        }
        unsigned int M = lmax, T0 = lmax;
        #pragma unroll
        for (int off = 32; off; off >>= 1) {
            unsigned int om = (unsigned int)__shfl_xor((int)M, off);
            unsigned int ot = (unsigned int)__shfl_xor((int)T0, off);
            M = om > M ? om : M;
            T0 = ot < T0 ? ot : T0;
        }
        // row max value (for exp stabilization) from inverse key map
        float mx = h2f((ushort_t)((M & 0x8000u) ? (M ^ 0x8000u) : (~M & 0xFFFFu)));
        unsigned int T;
        int hb;
        unsigned int diff = T0 ^ M;
        if (diff == 0u) { T = M; hb = -1; }
        else { hb = 31 - __builtin_clz(diff); T = M & ~((2u << hb) - 1u); }
        for (int bit = hb; bit >= 0; bit--) {
            unsigned int trial = T | (1u << bit);
            int c = 0;
            #pragma unroll
            for (int t = 0; t < 16; t++)
                c += __popcll(__ballot(kk[t] >= trial));
            if (c >= KTOP) {
                T = trial;
                if (c == KTOP) break;   // selected set already unique == top-64
            }
        }
        float ev[16]; float sum = 0.f;
        #pragma unroll
        for (int t = 0; t < 8; t++) {
            float sa = h2f((ushort_t)u0[t]);
            float ea = (kk[t] >= T) ? __expf(sa - mx) : 0.f;     // ties kept (matches >= kth)
            ev[t] = ea; sum += ea;
            float sb = h2f((ushort_t)u1[t]);
            float eb = (kk[8 + t] >= T) ? __expf(sb - mx) : 0.f;
            ev[8 + t] = eb; sum += eb;
        }
        #pragma unroll
        for (int off = 32; off; off >>= 1) sum += __shfl_xor(sum, off);
        float inv = 1.f / sum;
        ushortx8 w0, w1;
        #pragma unroll
        for (int t = 0; t < 8; t++) {
            w0[t] = f2h(ev[t] * inv);
            w1[t] = f2h(ev[8 + t] * inv);
        }
        *(ushortx8*)&Srow[lane * 8] = w0;
        *(ushortx8*)&Srow[(64 + lane) * 8] = w1;
    }
    __syncthreads();

    // ---- PV (f16 MFMA): attn(16 x 64) = W(16 x 1024) @ V(1024 x 64); wave wid owns d-tile wid*16
    // Two accumulators break the 32-long serial MFMA dependence chain.
    floatx4 o0 = (floatx4){0.f, 0.f, 0.f, 0.f};
    floatx4 o1 = (floatx4){0.f, 0.f, 0.f, 0.f};
    const _Float16* Srowp = Smh + (size_t)r * 1024;
    const int xr = r & 7;
    const ushort_t* vrow = vbase + (size_t)(wid * 16 + r) * S_;
    #pragma unroll 4
    for (int ks2 = 0; ks2 < 16; ks2++) {
        int ks = ks2 * 2;
        half8 wa0 = *(const half8*)&Srowp[((ks * 4 + quad) ^ xr) << 3];
        half8 wa1 = *(const half8*)&Srowp[(((ks + 1) * 4 + quad) ^ xr) << 3];
        half8 vb0 = *(const half8*)&vrow[ks * 32 + quad * 8];
        half8 vb1 = *(const half8*)&vrow[(ks + 1) * 32 + quad * 8];
        o0 = __builtin_amdgcn_mfma_f32_16x16x32_f16(wa0, vb0, o0, 0, 0, 0);
        o1 = __builtin_amdgcn_mfma_f32_16x16x32_f16(wa1, vb1, o1, 0, 0, 0);
    }
    floatx4 oacc = o0 + o1;
    #pragma unroll
    for (int i2 = 0; i2 < 4; i2++) {
        int row = quad * 4 + i2;
        attnb[((size_t)b * S_ + i0 + row) * D_ + h * HD_ + wid * 16 + r] = f2bf(oacc[i2]);
    }
}

// ---------------------------------------------------------------- layernorm kernels
__global__ __launch_bounds__(256) void ln1_kernel(const float* __restrict__ x,
                                                  const ushort_t* __restrict__ t,
                                                  const float* __restrict__ g,
                                                  const float* __restrict__ be,
                                                  ushort_t* __restrict__ hb) {
    int row = blockIdx.x, tid = threadIdx.x;
    const float* xr = x + (size_t)row * D_;
    const ushort_t* tr = t + (size_t)row * D_;
    float v[4]; float s = 0.f, s2 = 0.f;
    #pragma unroll
    for (int it = 0; it < 4; it++) {
        int j = tid + it * 256;
        v[it] = xr[j] + bf2f(tr[j]);
        s += v[it]; s2 += v[it] * v[it];
    }
    #pragma unroll
    for (int off = 32; off; off >>= 1) { s += __shfl_xor(s, off); s2 += __shfl_xor(s2, off); }
    __shared__ float rs[4], rq[4];
    if ((tid & 63) == 0) { rs[tid >> 6] = s; rq[tid >> 6] = s2; }
    __syncthreads();
    s = rs[0] + rs[1] + rs[2] + rs[3];
    s2 = rq[0] + rq[1] + rq[2] + rq[3];
    float mu = s * (1.f / D_);
    float var = s2 * (1.f / D_) - mu * mu;
    float rstd = rsqrtf(var + 1e-5f);
    #pragma unroll
    for (int it = 0; it < 4; it++) {
        int j = tid + it * 256;
        hb[(size_t)row * D_ + j] = f2bf((v[it] - mu) * rstd * g[j] + be[j]);
    }
}

__global__ __launch_bounds__(256) void ln2_kernel(const ushort_t* __restrict__ hbuf,
                                                  const ushort_t* __restrict__ t,
                                                  const float* __restrict__ g,
                                                  const float* __restrict__ be,
                                                  float* __restrict__ out) {
    int row = blockIdx.x, tid = threadIdx.x;
    const ushort_t* hr = hbuf + (size_t)row * D_;
    const ushort_t* tr = t + (size_t)row * D_;
    float v[4]; float s = 0.f, s2 = 0.f;
    #pragma unroll
    for (int it = 0; it < 4; it++) {
        int j = tid + it * 256;
        v[it] = bf2f(hr[j]) + bf2f(tr[j]);
        s += v[it]; s2 += v[it] * v[it];
    }
    #pragma unroll
    for (int off = 32; off; off >>= 1) { s += __shfl_xor(s, off); s2 += __shfl_xor(s2, off); }
    __shared__ float rs[4], rq[4];
    if ((tid & 63) == 0) { rs[tid >> 6] = s; rq[tid >> 6] = s2; }
    __syncthreads();
    s = rs[0] + rs[1] + rs[2] + rs[3];
    s2 = rq[0] + rq[1] + rq[2] + rq[3];
    float mu = s * (1.f / D_);
    float var = s2 * (1.f / D_) - mu * mu;
    float rstd = rsqrtf(var + 1e-5f);
    #pragma unroll
    for (int it = 0; it < 4; it++) {
        int j = tid + it * 256;
        out[(size_t)row * D_ + j] = (v[it] - mu) * rstd * g[j] + be[j];
    }
}

// ---------------------------------------------------------------- launch
extern "C" void kernel_launch(void* const* d_in, const int* in_sizes, int n_in,
                              void* d_out, int out_size, void* d_ws, size_t ws_size,
                              hipStream_t stream) {
    (void)in_sizes; (void)n_in; (void)out_size; (void)ws_size;
    const float* x   = (const float*)d_in[0];
    const int*   tok = (const int*)d_in[1];
    const float* pmi = (const float*)d_in[2];
    const float* Wq  = (const float*)d_in[3];
    const float* bq  = (const float*)d_in[4];
    const float* Wk  = (const float*)d_in[5];
    const float* bk  = (const float*)d_in[6];
    const float* Wv  = (const float*)d_in[7];
    const float* bv  = (const float*)d_in[8];
    const float* Wo  = (const float*)d_in[9];
    const float* bo  = (const float*)d_in[10];
    const float* W1  = (const float*)d_in[11];
    const float* b1  = (const float*)d_in[12];
    const float* W2  = (const float*)d_in[13];
    const float* b2  = (const float*)d_in[14];
    const float* g1  = (const float*)d_in[15];
    const float* be1 = (const float*)d_in[16];
    const float* g2  = (const float*)d_in[17];
    const float* be2 = (const float*)d_in[18];
    float* out = (float*)d_out;

    char* ws = (char*)d_ws;
    size_t off = 0;
    auto alloc = [&](size_t bytes) { char* p = ws + off; off += (bytes + 255) & ~(size_t)255; return p; };
    const size_t BSD = (size_t)B_ * S_ * D_;
    ushort_t* xb     = (ushort_t*)alloc(BSD * 2);                 // 16.8 MB
    ushort_t* WqkvT  = (ushort_t*)alloc((size_t)3 * D_ * D_ * 2); // 6 MB (q,k,v contiguous)
    ushort_t* WoT    = (ushort_t*)alloc((size_t)D_ * D_ * 2);
    ushort_t* W1T    = (ushort_t*)alloc((size_t)D_ * F_ * 2);
    ushort_t* W2T    = (ushort_t*)alloc((size_t)F_ * D_ * 2);
    float*    bqkv   = (float*)alloc(3072 * 4);
    ushort_t* qkvb   = (ushort_t*)alloc(3 * BSD * 2);             // 50 MB (q,k,v)
    ushort_t* vT     = (ushort_t*)alloc(BSD * 2);
    ushort_t* biasb  = (ushort_t*)alloc((size_t)B_ * S_ * S_ * 2);
    ushort_t* extra  = (ushort_t*)alloc(BSD * 2);
    (void)extra;
    // aliases (strict stream-order reuse)
    ushort_t* qb    = qkvb;
    ushort_t* kb    = qkvb + BSD;
    ushort_t* vb    = qkvb + 2 * BSD;
    ushort_t* attnb = xb;           // xb dead after QKV GEMM
    ushort_t* tbuf  = qb;           // q dead after attention
    ushort_t* hb    = kb;           // k dead after attention
    ushort_t* ffb   = vb;           // v+vT+biasb+extra (64MB contiguous) dead after attention

    const size_t attn_lds = 16 * 1024 * 2;                     // 32768 B

    cast_x_kernel<<<8192, 256, 0, stream>>>(x, xb);
    transpose_cast_kernel<<<dim3(32, 32), dim3(32, 8), 0, stream>>>(Wq, WqkvT, D_, D_, 0.125f);
    transpose_cast_kernel<<<dim3(32, 32), dim3(32, 8), 0, stream>>>(Wk, WqkvT + (size_t)D_ * D_, D_, D_, 1.0f);
    transpose_cast_kernel<<<dim3(32, 32), dim3(32, 8), 0, stream>>>(Wv, WqkvT + (size_t)2 * D_ * D_, D_, D_, 1.0f);
    transpose_cast_kernel<<<dim3(32, 32), dim3(32, 8), 0, stream>>>(Wo, WoT, D_, D_, 1.0f);
    transpose_cast_kernel<<<dim3(128, 32), dim3(32, 8), 0, stream>>>(W1, W1T, D_, F_, 1.0f);
    transpose_cast_kernel<<<dim3(32, 128), dim3(32, 8), 0, stream>>>(W2, W2T, F_, D_, 1.0f);
    pack_bias3_kernel<<<12, 256, 0, stream>>>(bq, bk, bv, bqkv);
    bias_gather_kernel<<<B_ * S_, 256, 0, stream>>>(tok, pmi, biasb);

    gemm_bt<<<dim3(24, 64), 256, 0, stream>>>(xb, WqkvT, bqkv, qkvb, B_ * S_, 3 * D_, D_, 2);
    transpose_v_kernel<<<B_ * H_ * (S_ / 64), 256, 0, stream>>>(vb, vT);

    attn_kernel<<<B_ * H_ * (S_ / 16), 256, attn_lds, stream>>>(qb, kb, vT, biasb, attnb);

    gemm_bt<<<dim3(8, 64), 256, 0, stream>>>(attnb, WoT, bo, tbuf, B_ * S_, D_, D_, 0);
    ln1_kernel<<<B_ * S_, 256, 0, stream>>>(x, tbuf, g1, be1, hb);
    gemm_bt<<<dim3(32, 64), 256, 0, stream>>>(hb, W1T, b1, ffb, B_ * S_, F_, D_, 1);
    gemm_bt<<<dim3(8, 64), 256, 0, stream>>>(ffb, W2T, b2, tbuf, B_ * S_, D_, F_, 0);
    ln2_kernel<<<B_ * S_, 256, 0, stream>>>(hb, tbuf, g2, be2, out);
}

// Round 3
// 1080.665 us; speedup vs baseline: 1.0909x; 1.0176x over previous
//
#include <hip/hip_runtime.h>
#include <cstdint>
#include <cstddef>

// Problem constants
#define B_   8
#define S_   1024
#define D_   1024
#define H_   16
#define HD_  64
#define F_   4096
#define V_   8192
#define KTOP 64

typedef unsigned short ushort_t;
typedef __attribute__((ext_vector_type(8))) short short8;            // MFMA bf16 A/B frag (4 VGPR)
typedef __attribute__((ext_vector_type(8))) _Float16 half8;          // MFMA f16 A/B frag
typedef __attribute__((ext_vector_type(4))) float floatx4;           // MFMA C/D frag
typedef __attribute__((ext_vector_type(4))) unsigned int uintx4;     // 16B copy
typedef __attribute__((ext_vector_type(4))) float floatv4;
typedef __attribute__((ext_vector_type(4))) unsigned short ushortx4;
typedef __attribute__((ext_vector_type(8))) unsigned short ushortx8;

__device__ __forceinline__ ushort_t f2bf(float f) {
    unsigned int u = __builtin_bit_cast(unsigned int, f);
    u += 0x7fffu + ((u >> 16) & 1u);            // round-to-nearest-even
    return (ushort_t)(u >> 16);
}
__device__ __forceinline__ float bf2f(ushort_t u) {
    unsigned int x = ((unsigned int)u) << 16;
    return __builtin_bit_cast(float, x);
}
__device__ __forceinline__ ushort_t f2h(float f) {
    _Float16 h = (_Float16)f;
    return __builtin_bit_cast(ushort_t, h);
}
__device__ __forceinline__ float h2f(ushort_t u) {
    return (float)__builtin_bit_cast(_Float16, u);
}

// async global->LDS, 16B per lane; lds dest = wave-uniform base + lane*16
__device__ __forceinline__ void gload_lds16(const ushort_t* g, ushort_t* lds_base) {
    __builtin_amdgcn_global_load_lds(
        (const __attribute__((address_space(1))) unsigned int*)g,
        (__attribute__((address_space(3))) unsigned int*)lds_base,
        16, 0, 0);
}

// ---------------------------------------------------------------- cast x -> bf16
__global__ __launch_bounds__(256) void cast_x_kernel(const float* __restrict__ x,
                                                     ushort_t* __restrict__ xb) {
    int gid = blockIdx.x * 256 + threadIdx.x;   // 4 elems per thread
    floatv4 v = ((const floatv4*)x)[gid];
    ushortx4 o;
    o[0] = f2bf(v[0]); o[1] = f2bf(v[1]); o[2] = f2bf(v[2]); o[3] = f2bf(v[3]);
    ((ushortx4*)xb)[gid] = o;
}

// ------------------------------------------- transpose + cast weight: W(K,N) -> WT(N,K) bf16, * scale
__global__ void transpose_cast_kernel(const float* __restrict__ W, ushort_t* __restrict__ WT,
                                      int K, int N, float scale) {
    __shared__ float tile[32][33];
    int n0 = blockIdx.x * 32, k0 = blockIdx.y * 32;
    #pragma unroll
    for (int i = threadIdx.y; i < 32; i += 8)
        tile[i][threadIdx.x] = W[(size_t)(k0 + i) * N + n0 + threadIdx.x];
    __syncthreads();
    #pragma unroll
    for (int i = threadIdx.y; i < 32; i += 8)
        WT[(size_t)(n0 + i) * K + k0 + threadIdx.x] = f2bf(tile[threadIdx.x][i] * scale);
}

// ---------------------------------------------------------------- pack q/k/v biases (bq scaled 1/8)
__global__ __launch_bounds__(256) void pack_bias3_kernel(const float* __restrict__ bq,
                                                         const float* __restrict__ bk,
                                                         const float* __restrict__ bv,
                                                         float* __restrict__ o) {
    int i = blockIdx.x * 256 + threadIdx.x;   // 3072 total
    float v = (i < 1024) ? bq[i] * 0.125f : (i < 2048) ? bk[i - 1024] : bv[i - 2048];
    o[i] = v;
}

// ---------------------------------------------------------------- pmi bias gather -> fp16 (ALPHA folded)
__global__ __launch_bounds__(256) void bias_gather_kernel(const int* __restrict__ tok,
                                                          const float* __restrict__ pmi,
                                                          ushort_t* __restrict__ biasb) {
    int b = blockIdx.x >> 10;
    int i = blockIdx.x & (S_ - 1);
    int ti = tok[b * S_ + i];
    const float* prow = pmi + (size_t)ti * V_;
    #pragma unroll
    for (int it = 0; it < 4; it++) {
        int j = threadIdx.x + it * 256;
        int tj = tok[b * S_ + j];
        biasb[(size_t)blockIdx.x * S_ + j] = f2h(0.1f * prow[tj]);
    }
}

// ---------------------------------------------------------------- V (B,H,S,HD) bf16 -> vT (B,H,HD,S) fp16
__global__ __launch_bounds__(256) void transpose_v_kernel(const ushort_t* __restrict__ v,
                                                          ushort_t* __restrict__ vT) {
    __shared__ ushort_t t[64 * 72];   // [s_loc][d], stride 72
    int bh = blockIdx.x >> 4;
    int s0 = (blockIdx.x & 15) * 64;
    #pragma unroll
    for (int it = 0; it < 2; it++) {
        int idx = threadIdx.x + it * 256;
        int sl = idx >> 3, dg = (idx & 7) * 8;
        *(uintx4*)&t[sl * 72 + dg] = *(const uintx4*)&v[((size_t)bh * S_ + s0 + sl) * HD_ + dg];
    }
    __syncthreads();
    #pragma unroll
    for (int it = 0; it < 2; it++) {
        int idx = threadIdx.x + it * 256;
        int dl = idx >> 3, sg = (idx & 7) * 8;
        ushortx8 o;
        #pragma unroll
        for (int i = 0; i < 8; i++) o[i] = f2h(bf2f(t[(sg + i) * 72 + dl]));
        *(ushortx8*)&vT[((size_t)bh * HD_ + dl) * S_ + s0 + sg] = o;
    }
}

// ---------------------------------------------------------------- GEMM: C = A(M,K) @ BT(N,K)^T + bias
// T3 minimum-2-phase: double-buffered LDS, prefetch tile t+1 issued BEFORE compute of
// tile t, single barrier per K-step (syncthreads drains vmcnt+lgkm => race-free).
// ep: 0 = bf16 row-major out ; 1 = + exact GELU ; 2 = fused QKV -> (3,B,H,S,HD)
__global__ __launch_bounds__(256) void gemm_bt(const ushort_t* __restrict__ A,
                                               const ushort_t* __restrict__ BT,
                                               const float* __restrict__ bias,
                                               ushort_t* __restrict__ C,
                                               int M, int N, int K, int ep) {
    __shared__ ushort_t As[2][128 * 32];   // unpadded: required by global_load_lds lane mapping
    __shared__ ushort_t Bs[2][128 * 32];

    const int tid = threadIdx.x;
    const int wid = tid >> 6, lane = tid & 63;
    const int quad = lane >> 4, r = lane & 15;
    const int wr = wid >> 1, wc = wid & 1;
    const int m0 = blockIdx.y * 128, n0 = blockIdx.x * 128;

    floatx4 acc[4][4];
    #pragma unroll
    for (int a = 0; a < 4; a++)
        #pragma unroll
        for (int b = 0; b < 4; b++) acc[a][b] = (floatx4){0.f, 0.f, 0.f, 0.f};

    // staging map: wave wid covers 16 rows/call; lane -> (row=lane>>2, col8=(lane&3)*8)
    const int srow = wid * 16 + (lane >> 2);
    const int scol = (lane & 3) * 8;
    const ushort_t* Ag0 = A + (size_t)(m0 + srow) * K + scol;
    const ushort_t* Ag1 = A + (size_t)(m0 + 64 + srow) * K + scol;
    const ushort_t* Bg0 = BT + (size_t)(n0 + srow) * K + scol;
    const ushort_t* Bg1 = BT + (size_t)(n0 + 64 + srow) * K + scol;
    const int d0 = (wid * 16) * 32;
    const int d1 = (64 + wid * 16) * 32;

    // prologue: stage K-tile 0 into buffer 0
    gload_lds16(Ag0, &As[0][d0]);
    gload_lds16(Ag1, &As[0][d1]);
    gload_lds16(Bg0, &Bs[0][d0]);
    gload_lds16(Bg1, &Bs[0][d1]);
    __syncthreads();

    int cur = 0;
    for (int k0 = 0; k0 < K; k0 += 32) {
        const int nxt = cur ^ 1;
        if (k0 + 32 < K) {      // issue next-tile prefetch FIRST; hides under MFMA below
            gload_lds16(Ag0 + k0 + 32, &As[nxt][d0]);
            gload_lds16(Ag1 + k0 + 32, &As[nxt][d1]);
            gload_lds16(Bg0 + k0 + 32, &Bs[nxt][d0]);
            gload_lds16(Bg1 + k0 + 32, &Bs[nxt][d1]);
        }
        short8 af[4], bf[4];
        #pragma unroll
        for (int t = 0; t < 4; t++)
            af[t] = *(const short8*)&As[cur][(wr * 64 + t * 16 + r) * 32 + quad * 8];
        #pragma unroll
        for (int t = 0; t < 4; t++)
            bf[t] = *(const short8*)&Bs[cur][(wc * 64 + t * 16 + r) * 32 + quad * 8];
        #pragma unroll
        for (int tm = 0; tm < 4; tm++)
            #pragma unroll
            for (int tn = 0; tn < 4; tn++)
                acc[tm][tn] = __builtin_amdgcn_mfma_f32_16x16x32_bf16(af[tm], bf[tn], acc[tm][tn], 0, 0, 0);
        __syncthreads();        // drains prefetch (vmcnt0) + ds_reads (lgkm0), then barrier
        cur = nxt;
    }

    #pragma unroll
    for (int tm = 0; tm < 4; tm++) {
        #pragma unroll
        for (int tn = 0; tn < 4; tn++) {
            const int n = n0 + wc * 64 + tn * 16 + r;      // C col = lane&15 (m89-verified)
            const float bv = bias[n];
            #pragma unroll
            for (int i2 = 0; i2 < 4; i2++) {
                const int m = m0 + wr * 64 + tm * 16 + quad * 4 + i2;  // row = quad*4+reg
                float v = acc[tm][tn][i2] + bv;
                if (ep == 1) v = 0.5f * v * (1.0f + erff(v * 0.70710678118654752f));
                size_t idx;
                if (ep == 2) {
                    // (b,s) x (tensor,h,d) -> tensor*(B,H,S,HD)
                    int tensor = n >> 10, nn = n & 1023;
                    idx = (size_t)tensor * (B_ * S_ * D_)
                        + (((size_t)(m >> 10) * H_ + (nn >> 6)) * S_ + (m & (S_ - 1))) * HD_ + (nn & (HD_ - 1));
                } else {
                    idx = (size_t)m * N + n;
                }
                C[idx] = f2bf(v);
            }
        }
    }
}

// ---------------------------------------------------------------- fused attention (per b,h,16-query tile)
// 512 threads / 8 waves, 16-query tile, LDS 32768 B -> 4 blocks/CU = 32 waves/CU (100% occupancy).
// Latency-bound kernel: doubling resident waves halves the per-wave serial path and hides it.
// Work split: bias stage 4 chunks/wave; QK^T key-tiles kt = t*8+wid (8 iters/wave);
// select 2 rows/wave; PV d-tile = wid&3 with ks-half = wid>>2 + cross-wave LDS reduction.
// Scores 16x1024 fp16 XOR-block-swizzled (block L holds col-block L^(row&7)) as before.
__global__ __launch_bounds__(512) void attn_kernel(const ushort_t* __restrict__ q,
                                                   const ushort_t* __restrict__ k,
                                                   const ushort_t* __restrict__ vT,
                                                   const ushort_t* __restrict__ biasb,
                                                   ushort_t* __restrict__ attnb) {
    extern __shared__ char smem[];
    ushort_t* Sm = (ushort_t*)smem;                 // 16 x 1024 fp16, swizzled
    _Float16* Smh = (_Float16*)smem;

    const int bid = blockIdx.x;
    const int b = bid >> 10;
    const int h = (bid >> 6) & (H_ - 1);
    const int i0 = (bid & 63) * 16;
    const int tid = threadIdx.x;
    const int wid = tid >> 6, lane = tid & 63;
    const int quad = lane >> 4, r = lane & 15;

    const size_t bh = (size_t)b * H_ + h;
    const ushort_t* qbase = q + bh * S_ * HD_;
    const ushort_t* kbase = k + bh * S_ * HD_;
    const ushort_t* vbase = vT + bh * HD_ * S_;
    const ushort_t* bsrc = biasb + ((size_t)b * S_ + i0) * S_;  // 16 rows, contiguous 32KB

    // stage bias fp16 via async global->LDS: 32 chunks of 1KB, 4 per wave.
    // LDS dest linear; source lane index pre-swizzled (lane ^ (row&7)).
    #pragma unroll
    for (int c8 = 0; c8 < 4; c8++) {
        int c = wid * 4 + c8;
        int row = c >> 1, half = c & 1;
        int xr = row & 7;
        gload_lds16(bsrc + (size_t)row * S_ + half * 512 + (lane ^ xr) * 8,
                    Sm + row * 1024 + half * 512);
    }
    // q fragments straight from global (per-lane loads; L1/L2-hit, wave redundancy is free)
    short8 aq0 = *(const short8*)&qbase[(size_t)(i0 + r) * HD_ + quad * 8];
    short8 aq1 = *(const short8*)&qbase[(size_t)(i0 + r) * HD_ + 32 + quad * 8];
    __syncthreads();

    // ---- QK^T (swapped operands): S^T tile = K_frag * Q_frag; kt = t*8 + wid.
    // cb = 2*kt + (quad>>1) = 16t + 8*(wid>>2) + (2*(wid&3)+(quad>>1)); 3-bit XOR swizzle
    // touches only the low3 part -> la = labase + t*128.
    const int q1 = quad >> 1;
    const int xr0 = r & 7;
    const int labase = r * 1024 + ((((wid & 3) * 2 + q1) ^ xr0) << 3)
                     + ((wid >> 2) << 6) + (quad & 1) * 4;
    const ushort_t* kpl = kbase + (size_t)(wid * 16 + r) * HD_ + quad * 8;
    #pragma unroll
    for (int t = 0; t < 8; t++) {
        const int la = labase + t * 128;
        ushortx4 bi = *(const ushortx4*)&Sm[la];
        floatx4 acc;
        acc[0] = h2f(bi[0]); acc[1] = h2f(bi[1]); acc[2] = h2f(bi[2]); acc[3] = h2f(bi[3]);
        const ushort_t* kp = kpl + (size_t)t * 128 * HD_;
        short8 b0 = *(const short8*)kp;
        short8 b1 = *(const short8*)(kp + 32);
        acc = __builtin_amdgcn_mfma_f32_16x16x32_bf16(b0, aq0, acc, 0, 0, 0);
        acc = __builtin_amdgcn_mfma_f32_16x16x32_bf16(b1, aq1, acc, 0, 0, 0);
        ushortx4 so;
        so[0] = f2h(acc[0]); so[1] = f2h(acc[1]); so[2] = f2h(acc[2]); so[3] = f2h(acc[3]);
        *(ushortx4*)&Sm[la] = so;
    }
    __syncthreads();

    // ---- exact top-64 on fp16 scores: 16-bit radix select, ballot-counted. 2 rows/wave.
    for (int rr = 0; rr < 2; rr++) {
        int row = wid * 2 + rr;
        ushort_t* Srow = Sm + row * 1024;
        ushortx8 u0 = *(const ushortx8*)&Srow[lane * 8];
        ushortx8 u1 = *(const ushortx8*)&Srow[(64 + lane) * 8];
        unsigned int kk[16];
        unsigned int lmax = 0u;
        #pragma unroll
        for (int t = 0; t < 8; t++) {
            unsigned int ua = u0[t];
            kk[t] = ua ^ ((ua & 0x8000u) ? 0xFFFFu : 0x8000u);   // order-preserving key map
            lmax = kk[t] > lmax ? kk[t] : lmax;
            unsigned int ub = u1[t];
            kk[8 + t] = ub ^ ((ub & 0x8000u) ? 0xFFFFu : 0x8000u);
            lmax = kk[8 + t] > lmax ? kk[8 + t] : lmax;
        }
        unsigned int M = lmax, T0 = lmax;
        #pragma unroll
        for (int off = 32; off; off >>= 1) {
            unsigned int om = (unsigned int)__shfl_xor((int)M, off);
            unsigned int ot = (unsigned int)__shfl_xor((int)T0, off);
            M = om > M ? om : M;
            T0 = ot < T0 ? ot : T0;
        }
        // row max value (for exp stabilization) from inverse key map
        float mx = h2f((ushort_t)((M & 0x8000u) ? (M ^ 0x8000u) : (~M & 0xFFFFu)));
        unsigned int T;
        int hb;
        unsigned int diff = T0 ^ M;
        if (diff == 0u) { T = M; hb = -1; }
        else { hb = 31 - __builtin_clz(diff); T = M & ~((2u << hb) - 1u); }
        for (int bit = hb; bit >= 0; bit--) {
            unsigned int trial = T | (1u << bit);
            int c = 0;
            #pragma unroll
            for (int t = 0; t < 16; t++)
                c += __popcll(__ballot(kk[t] >= trial));
            if (c >= KTOP) {
                T = trial;
                if (c == KTOP) break;   // selected set already unique == top-64
            }
        }
        float ev[16]; float sum = 0.f;
        #pragma unroll
        for (int t = 0; t < 8; t++) {
            float sa = h2f((ushort_t)u0[t]);
            float ea = (kk[t] >= T) ? __expf(sa - mx) : 0.f;     // ties kept (matches >= kth)
            ev[t] = ea; sum += ea;
            float sb = h2f((ushort_t)u1[t]);
            float eb = (kk[8 + t] >= T) ? __expf(sb - mx) : 0.f;
            ev[8 + t] = eb; sum += eb;
        }
        #pragma unroll
        for (int off = 32; off; off >>= 1) sum += __shfl_xor(sum, off);
        float inv = 1.f / sum;
        ushortx8 w0, w1;
        #pragma unroll
        for (int t = 0; t < 8; t++) {
            w0[t] = f2h(ev[t] * inv);
            w1[t] = f2h(ev[8 + t] * inv);
        }
        *(ushortx8*)&Srow[lane * 8] = w0;
        *(ushortx8*)&Srow[(64 + lane) * 8] = w1;
    }
    __syncthreads();

    // ---- PV (f16 MFMA): attn(16 x 64) = W(16 x 1024) @ V(1024 x 64).
    // 8 waves: d-tile = wid&3, ks-half = wid>>2 (16 of 32 k-slices each); two accumulators
    // break the serial MFMA chain; cross-wave reduction through 4KB of the (now dead) score LDS.
    const int dt = wid & 3, ksh = wid >> 2;
    floatx4 o0 = (floatx4){0.f, 0.f, 0.f, 0.f};
    floatx4 o1 = (floatx4){0.f, 0.f, 0.f, 0.f};
    const _Float16* Srowp = Smh + (size_t)r * 1024;
    const int xr = r & 7;
    const ushort_t* vrow = vbase + (size_t)(dt * 16 + r) * S_;
    #pragma unroll
    for (int kss = 0; kss < 8; kss++) {
        int ks = ksh * 16 + kss * 2;
        half8 wa0 = *(const half8*)&Srowp[((ks * 4 + quad) ^ xr) << 3];
        half8 wa1 = *(const half8*)&Srowp[(((ks + 1) * 4 + quad) ^ xr) << 3];
        half8 vb0 = *(const half8*)&vrow[ks * 32 + quad * 8];
        half8 vb1 = *(const half8*)&vrow[(ks + 1) * 32 + quad * 8];
        o0 = __builtin_amdgcn_mfma_f32_16x16x32_f16(wa0, vb0, o0, 0, 0, 0);
        o1 = __builtin_amdgcn_mfma_f32_16x16x32_f16(wa1, vb1, o1, 0, 0, 0);
    }
    floatx4 oacc = o0 + o1;
    __syncthreads();                       // all PV score-reads complete; LDS reusable
    float* red = (float*)smem;             // 4 d-tiles x 16 rows x 16 cols fp32 = 4KB
    if (ksh == 1) {
        #pragma unroll
        for (int i2 = 0; i2 < 4; i2++)
            red[dt * 256 + (quad * 4 + i2) * 16 + r] = oacc[i2];
    }
    __syncthreads();
    if (ksh == 0) {
        #pragma unroll
        for (int i2 = 0; i2 < 4; i2++) {
            int row = quad * 4 + i2;
            float v = oacc[i2] + red[dt * 256 + row * 16 + r];
            attnb[((size_t)b * S_ + i0 + row) * D_ + h * HD_ + dt * 16 + r] = f2bf(v);
        }
    }
}

// ---------------------------------------------------------------- layernorm kernels
__global__ __launch_bounds__(256) void ln1_kernel(const float* __restrict__ x,
                                                  const ushort_t* __restrict__ t,
                                                  const float* __restrict__ g,
                                                  const float* __restrict__ be,
                                                  ushort_t* __restrict__ hb) {
    int row = blockIdx.x, tid = threadIdx.x;
    const float* xr = x + (size_t)row * D_;
    const ushort_t* tr = t + (size_t)row * D_;
    float v[4]; float s = 0.f, s2 = 0.f;
    #pragma unroll
    for (int it = 0; it < 4; it++) {
        int j = tid + it * 256;
        v[it] = xr[j] + bf2f(tr[j]);
        s += v[it]; s2 += v[it] * v[it];
    }
    #pragma unroll
    for (int off = 32; off; off >>= 1) { s += __shfl_xor(s, off); s2 += __shfl_xor(s2, off); }
    __shared__ float rs[4], rq[4];
    if ((tid & 63) == 0) { rs[tid >> 6] = s; rq[tid >> 6] = s2; }
    __syncthreads();
    s = rs[0] + rs[1] + rs[2] + rs[3];
    s2 = rq[0] + rq[1] + rq[2] + rq[3];
    float mu = s * (1.f / D_);
    float var = s2 * (1.f / D_) - mu * mu;
    float rstd = rsqrtf(var + 1e-5f);
    #pragma unroll
    for (int it = 0; it < 4; it++) {
        int j = tid + it * 256;
        hb[(size_t)row * D_ + j] = f2bf((v[it] - mu) * rstd * g[j] + be[j]);
    }
}

__global__ __launch_bounds__(256) void ln2_kernel(const ushort_t* __restrict__ hbuf,
                                                  const ushort_t* __restrict__ t,
                                                  const float* __restrict__ g,
                                                  const float* __restrict__ be,
                                                  float* __restrict__ out) {
    int row = blockIdx.x, tid = threadIdx.x;
    const ushort_t* hr = hbuf + (size_t)row * D_;
    const ushort_t* tr = t + (size_t)row * D_;
    float v[4]; float s = 0.f, s2 = 0.f;
    #pragma unroll
    for (int it = 0; it < 4; it++) {
        int j = tid + it * 256;
        v[it] = bf2f(hr[j]) + bf2f(tr[j]);
        s += v[it]; s2 += v[it] * v[it];
    }
    #pragma unroll
    for (int off = 32; off; off >>= 1) { s += __shfl_xor(s, off); s2 += __shfl_xor(s2, off); }
    __shared__ float rs[4], rq[4];
    if ((tid & 63) == 0) { rs[tid >> 6] = s; rq[tid >> 6] = s2; }
    __syncthreads();
    s = rs[0] + rs[1] + rs[2] + rs[3];
    s2 = rq[0] + rq[1] + rq[2] + rq[3];
    float mu = s * (1.f / D_);
    float var = s2 * (1.f / D_) - mu * mu;
    float rstd = rsqrtf(var + 1e-5f);
    #pragma unroll
    for (int it = 0; it < 4; it++) {
        int j = tid + it * 256;
        out[(size_t)row * D_ + j] = (v[it] - mu) * rstd * g[j] + be[j];
    }
}

// ---------------------------------------------------------------- launch
extern "C" void kernel_launch(void* const* d_in, const int* in_sizes, int n_in,
                              void* d_out, int out_size, void* d_ws, size_t ws_size,
                              hipStream_t stream) {
    (void)in_sizes; (void)n_in; (void)out_size; (void)ws_size;
    const float* x   = (const float*)d_in[0];
    const int*   tok = (const int*)d_in[1];
    const float* pmi = (const float*)d_in[2];
    const float* Wq  = (const float*)d_in[3];
    const float* bq  = (const float*)d_in[4];
    const float* Wk  = (const float*)d_in[5];
    const float* bk  = (const float*)d_in[6];
    const float* Wv  = (const float*)d_in[7];
    const float* bv  = (const float*)d_in[8];
    const float* Wo  = (const float*)d_in[9];
    const float* bo  = (const float*)d_in[10];
    const float* W1  = (const float*)d_in[11];
    const float* b1  = (const float*)d_in[12];
    const float* W2  = (const float*)d_in[13];
    const float* b2  = (const float*)d_in[14];
    const float* g1  = (const float*)d_in[15];
    const float* be1 = (const float*)d_in[16];
    const float* g2  = (const float*)d_in[17];
    const float* be2 = (const float*)d_in[18];
    float* out = (float*)d_out;

    char* ws = (char*)d_ws;
    size_t off = 0;
    auto alloc = [&](size_t bytes) { char* p = ws + off; off += (bytes + 255) & ~(size_t)255; return p; };
    const size_t BSD = (size_t)B_ * S_ * D_;
    ushort_t* xb     = (ushort_t*)alloc(BSD * 2);                 // 16.8 MB
    ushort_t* WqkvT  = (ushort_t*)alloc((size_t)3 * D_ * D_ * 2); // 6 MB (q,k,v contiguous)
    ushort_t* WoT    = (ushort_t*)alloc((size_t)D_ * D_ * 2);
    ushort_t* W1T    = (ushort_t*)alloc((size_t)D_ * F_ * 2);
    ushort_t* W2T    = (ushort_t*)alloc((size_t)F_ * D_ * 2);
    float*    bqkv   = (float*)alloc(3072 * 4);
    ushort_t* qkvb   = (ushort_t*)alloc(3 * BSD * 2);             // 50 MB (q,k,v)
    ushort_t* vT     = (ushort_t*)alloc(BSD * 2);
    ushort_t* biasb  = (ushort_t*)alloc((size_t)B_ * S_ * S_ * 2);
    ushort_t* extra  = (ushort_t*)alloc(BSD * 2);
    (void)extra;
    // aliases (strict stream-order reuse)
    ushort_t* qb    = qkvb;
    ushort_t* kb    = qkvb + BSD;
    ushort_t* vb    = qkvb + 2 * BSD;
    ushort_t* attnb = xb;           // xb dead after QKV GEMM
    ushort_t* tbuf  = qb;           // q dead after attention
    ushort_t* hb    = kb;           // k dead after attention
    ushort_t* ffb   = vb;           // v+vT+biasb+extra (64MB contiguous) dead after attention

    const size_t attn_lds = 16 * 1024 * 2;                     // 32768 B -> 4 blocks/CU @ 512 thr

    cast_x_kernel<<<8192, 256, 0, stream>>>(x, xb);
    transpose_cast_kernel<<<dim3(32, 32), dim3(32, 8), 0, stream>>>(Wq, WqkvT, D_, D_, 0.125f);
    transpose_cast_kernel<<<dim3(32, 32), dim3(32, 8), 0, stream>>>(Wk, WqkvT + (size_t)D_ * D_, D_, D_, 1.0f);
    transpose_cast_kernel<<<dim3(32, 32), dim3(32, 8), 0, stream>>>(Wv, WqkvT + (size_t)2 * D_ * D_, D_, D_, 1.0f);
    transpose_cast_kernel<<<dim3(32, 32), dim3(32, 8), 0, stream>>>(Wo, WoT, D_, D_, 1.0f);
    transpose_cast_kernel<<<dim3(128, 32), dim3(32, 8), 0, stream>>>(W1, W1T, D_, F_, 1.0f);
    transpose_cast_kernel<<<dim3(32, 128), dim3(32, 8), 0, stream>>>(W2, W2T, F_, D_, 1.0f);
    pack_bias3_kernel<<<12, 256, 0, stream>>>(bq, bk, bv, bqkv);
    bias_gather_kernel<<<B_ * S_, 256, 0, stream>>>(tok, pmi, biasb);

    gemm_bt<<<dim3(24, 64), 256, 0, stream>>>(xb, WqkvT, bqkv, qkvb, B_ * S_, 3 * D_, D_, 2);
    transpose_v_kernel<<<B_ * H_ * (S_ / 64), 256, 0, stream>>>(vb, vT);

    attn_kernel<<<B_ * H_ * (S_ / 16), 512, attn_lds, stream>>>(qb, kb, vT, biasb, attnb);

    gemm_bt<<<dim3(8, 64), 256, 0, stream>>>(attnb, WoT, bo, tbuf, B_ * S_, D_, D_, 0);
    ln1_kernel<<<B_ * S_, 256, 0, stream>>>(x, tbuf, g1, be1, hb);
    gemm_bt<<<dim3(32, 64), 256, 0, stream>>>(hb, W1T, b1, ffb, B_ * S_, F_, D_, 1);
    gemm_bt<<<dim3(8, 64), 256, 0, stream>>>(ffb, W2T, b2, tbuf, B_ * S_, D_, F_, 0);
    ln2_kernel<<<B_ * S_, 256, 0, stream>>>(hb, tbuf, g2, be2, out);
}